// Round 9
// baseline (342.355 us; speedup 1.0000x reference)
//
#include <hip/hip_runtime.h>
#include <hip/hip_bf16.h>
#include <math.h>

#define Bb 256
#define Nn 2048
#define Cc 128
#define Hh 64
#define Mm 50

// ---------------- K2: prob MLP, LDS-tiled GEMM ----------------
// 256 threads/block, 64 rows x 64 cols per block (32 blocks/batch).
// Phase 2: thread (rt=tid>>4, ct=tid&15) owns rows rt*4..+3 x cols {ct,ct+16,ct+32,ct+48}.
// h[16] only => no spill/chunk risk. All inner-loop operands from LDS.
__global__ __launch_bounds__(256, 4) void k_mlp_p(
    const float* __restrict__ feat, const float* __restrict__ cand,
    const float* __restrict__ p_w1, const float* __restrict__ p_b1,
    const float* __restrict__ p_g1, const float* __restrict__ p_be1,
    const float* __restrict__ p_w2, const float* __restrict__ p_b2,
    const float* __restrict__ p_g2, const float* __restrict__ p_be2,
    const float* __restrict__ p_w3, const float* __restrict__ p_b3,
    float* __restrict__ logits)
{
    __shared__ __attribute__((aligned(16))) float smem[9024];   // 36096 B
    float*  a_t = smem;                       // [64][64] t/a transposed (j-major); floats 0..4095
    float*  h_s = smem;                       // alias:   [64][65] h row-major;    floats 0..4159
    float*  w2s = smem + 4160;                // [64][64] w2;                      floats 4160..8255
    float4* uvb = (float4*)(smem + 8256);     // [64] {u,v,base,-}
    float2* gb1 = (float2*)(smem + 8512);     // [64] {g1,be1}
    float4* pk  = (float4*)(smem + 8640);     // [64] {g2,be2,w3,b2}
    float2* msg = (float2*)(smem + 8896);     // [64] {mu,rstd}

    int tid = threadIdx.x;
    int b = blockIdx.x >> 5;                  // 32 blocks x 64 rows = 2048 rows/batch
    int row0 = (blockIdx.x & 31) << 6;

    // ---- phase 0: stage w2 (all threads) + params + per-batch base (EXACT c-chain) ----
    {
        const float4* w2v = (const float4*)p_w2;
        float4* dst = (float4*)w2s;
        #pragma unroll
        for (int q = 0; q < 4; ++q) dst[tid + q * 256] = w2v[tid + q * 256];
    }
    if (tid < Hh) {
        gb1[tid] = make_float2(p_g1[tid], p_be1[tid]);
        pk[tid]  = make_float4(p_g2[tid], p_be2[tid], p_w3[tid], p_b2[tid]);
        const float* f = feat + b * Cc;
        float s = p_b1[tid];
        #pragma unroll 8
        for (int c = 0; c < Cc; ++c) s = fmaf(f[c], p_w1[c * Hh + tid], s);
        uvb[tid] = make_float4(p_w1[128 * Hh + tid], p_w1[129 * Hh + tid], s, 0.f);
    }
    __syncthreads();

    // ---- phase 1a: t-values into a_t[j][r]; thread (r=tid&63, jblk=tid>>6) does 16 j ----
    {
        int r = tid & 63, jblk = tid >> 6;
        float2 c2 = ((const float2*)cand)[(long)b * Nn + row0 + r];
        float cx = c2.x, cy = c2.y;
        #pragma unroll
        for (int jj = 0; jj < 16; ++jj) {
            int j = jblk * 16 + jj;                       // wave-uniform j
            float4 w = uvb[j];
            a_t[j * 64 + r] = fmaf(cy, w.y, fmaf(cx, w.x, w.z));
        }
    }
    __syncthreads();

    // ---- phase 1b: LN1 stats per row, sequential j (bit-exact); threads 0..63 ----
    if (tid < 64) {
        float sum = 0.f, sq = 0.f;
        #pragma unroll
        for (int j = 0; j < Hh; ++j) {
            float t = a_t[j * 64 + tid];
            sum += t;
            sq = fmaf(t, t, sq);
        }
        float mu = sum * (1.f / Hh);
        float rstd = rsqrtf(sq * (1.f / Hh) - mu * mu + 1e-5f);
        msg[tid] = make_float2(mu, rstd);
    }
    __syncthreads();

    // ---- phase 1c: apply LN1+ReLU in place (all threads, 16 j each) ----
    {
        int r = tid & 63, jblk = tid >> 6;
        float2 ms = msg[r];
        #pragma unroll
        for (int jj = 0; jj < 16; ++jj) {
            int j = jblk * 16 + jj;
            float t = a_t[j * 64 + r];
            float2 g = gb1[j];
            a_t[j * 64 + r] = fmaxf(fmaf((t - ms.x) * ms.y, g.x, g.y), 0.f);
        }
    }
    __syncthreads();

    // ---- phase 2: GEMM, h[16] (4 rows x 4 stride-16 cols), j ascending per chain ----
    int rt = tid >> 4, ct = tid & 15;
    float h[16];
    #pragma unroll
    for (int i = 0; i < 16; ++i) h[i] = 0.f;
    #pragma unroll 4
    for (int j = 0; j < Hh; ++j) {
        float4 av = *(const float4*)(a_t + j * 64 + rt * 4);
        float w0 = w2s[j * 64 + ct];
        float w1 = w2s[j * 64 + ct + 16];
        float w2 = w2s[j * 64 + ct + 32];
        float w3 = w2s[j * 64 + ct + 48];
        h[0]  = fmaf(av.x, w0, h[0]);  h[1]  = fmaf(av.x, w1, h[1]);
        h[2]  = fmaf(av.x, w2, h[2]);  h[3]  = fmaf(av.x, w3, h[3]);
        h[4]  = fmaf(av.y, w0, h[4]);  h[5]  = fmaf(av.y, w1, h[5]);
        h[6]  = fmaf(av.y, w2, h[6]);  h[7]  = fmaf(av.y, w3, h[7]);
        h[8]  = fmaf(av.z, w0, h[8]);  h[9]  = fmaf(av.z, w1, h[9]);
        h[10] = fmaf(av.z, w2, h[10]); h[11] = fmaf(av.z, w3, h[11]);
        h[12] = fmaf(av.w, w0, h[12]); h[13] = fmaf(av.w, w1, h[13]);
        h[14] = fmaf(av.w, w2, h[14]); h[15] = fmaf(av.w, w3, h[15]);
    }
    __syncthreads();                          // all a_t reads done before h_s overwrite

    // ---- phase 3: scatter h into h_s[row][col], stride-16 cols -> ~2-way banks ----
    #pragma unroll
    for (int rr = 0; rr < 4; ++rr) {
        float* dst = h_s + (rt * 4 + rr) * 65 + ct;
        dst[0]  = h[rr * 4 + 0];
        dst[16] = h[rr * 4 + 1];
        dst[32] = h[rr * 4 + 2];
        dst[48] = h[rr * 4 + 3];
    }
    __syncthreads();

    // ---- phase 4: per-row LN2 + head, sequential i (bit-exact); threads 0..63 ----
    if (tid < 64) {
        const float* hr = h_s + tid * 65;
        float sum2 = 0.f, sq2 = 0.f;
        #pragma unroll
        for (int i = 0; i < Hh; ++i) {
            float hv = hr[i] + pk[i].w;
            sum2 += hv;
            sq2 = fmaf(hv, hv, sq2);
        }
        float mu2 = sum2 * (1.f / Hh);
        float rstd2 = rsqrtf(sq2 * (1.f / Hh) - mu2 * mu2 + 1e-5f);
        float lg = p_b3[0];
        #pragma unroll
        for (int i = 0; i < Hh; ++i) {
            float4 k4 = pk[i];
            float hv = hr[i] + k4.w;
            float aa = fmaxf(fmaf((hv - mu2) * rstd2, k4.x, k4.y), 0.f);
            lg = fmaf(aa, k4.z, lg);
        }
        logits[(long)b * Nn + row0 + tid] = lg;
    }
}

// ---------------- K3: fused per-batch softmax + BCE partial + top-50 ----------------
__global__ __launch_bounds__(256) void k_post(
    const float* __restrict__ logits, const float* __restrict__ mask,
    const float* __restrict__ gt,
    float* __restrict__ bce_part, int* __restrict__ selidx_g, int* __restrict__ gidx_g)
{
    __shared__ float vals[Nn];
    __shared__ float redf[4];
    __shared__ float wvv[4]; __shared__ int wvi[4];
    __shared__ int   gidx_sh;
    __shared__ int   wini_sh;
    __shared__ int   selidx[Mm];

    int b = blockIdx.x, tid = threadIdx.x;
    int wave = tid >> 6, lane = tid & 63;
    const float* lg = logits + (long)b * Nn;
    const float* mk = mask + (long)b * Nn;

    float xv[8];
    float mx = -1e30f;
    #pragma unroll
    for (int k = 0; k < 8; ++k) {
        int n = tid + k * 256;
        xv[k] = lg[n] + mk[n];
        mx = fmaxf(mx, xv[k]);
    }
    #pragma unroll
    for (int m = 1; m < 64; m <<= 1) mx = fmaxf(mx, __shfl_xor(mx, m));
    if (lane == 0) redf[wave] = mx;
    __syncthreads();
    float m = fmaxf(fmaxf(redf[0], redf[1]), fmaxf(redf[2], redf[3]));
    __syncthreads();

    float ev[8]; float es = 0.f;
    #pragma unroll
    for (int k = 0; k < 8; ++k) { ev[k] = expf(xv[k] - m); es += ev[k]; }
    #pragma unroll
    for (int mm = 1; mm < 64; mm <<= 1) es += __shfl_xor(es, mm);
    if (lane == 0) redf[wave] = es;
    __syncthreads();
    float invZ = 1.f / (((redf[0] + redf[1]) + redf[2]) + redf[3]);

    const float* g = gt + (long)b * Nn;
    float bs = 0.f;
    #pragma unroll
    for (int k = 0; k < 8; ++k) {
        int n = tid + k * 256;
        float pv = ev[k] * invZ;
        vals[n] = pv;
        float gv = g[n];
        float lp = fmaxf(logf(pv), -100.f);
        float l1p = fmaxf(log1pf(-pv), -100.f);
        bs += gv * lp + (1.f - gv) * l1p;
        if (gv > 0.5f) gidx_sh = n;
    }
    #pragma unroll
    for (int mm = 1; mm < 64; mm <<= 1) bs += __shfl_xor(bs, mm);
    if (lane == 0) redf[wave] = bs;
    __syncthreads();
    if (tid == 0) {
        bce_part[b] = ((redf[0] + redf[1]) + redf[2]) + redf[3];
        gidx_g[b] = gidx_sh;
    }

    float bv = -1.f; int bi = 0x7fffffff;
    #pragma unroll
    for (int k = 0; k < 8; ++k) {
        int n = tid + k * 256;
        float v = vals[n];
        if (v > bv) { bv = v; bi = n; }
    }
    for (int it = 0; it < Mm; ++it) {
        float rv = bv; int ri = bi;
        #pragma unroll
        for (int mm = 1; mm < 64; mm <<= 1) {
            float v2 = __shfl_xor(rv, mm); int i2 = __shfl_xor(ri, mm);
            if (v2 > rv || (v2 == rv && i2 < ri)) { rv = v2; ri = i2; }
        }
        if (lane == 0) { wvv[wave] = rv; wvi[wave] = ri; }
        __syncthreads();
        if (tid == 0) {
            float wv = wvv[0]; int wi = wvi[0];
            #pragma unroll
            for (int k = 1; k < 4; ++k) {
                if (wvv[k] > wv || (wvv[k] == wv && wvi[k] < wi)) { wv = wvv[k]; wi = wvi[k]; }
            }
            wini_sh = wi;
            selidx[it] = wi;
        }
        __syncthreads();
        int wi = wini_sh;
        if ((wi & 255) == tid) {
            vals[wi] = -1.f;
            bv = -1.f; bi = 0x7fffffff;
            #pragma unroll
            for (int k = 0; k < 8; ++k) {
                int n = tid + k * 256;
                float v = vals[n];
                if (v > bv) { bv = v; bi = n; }
            }
        }
    }
    if (tid < Mm) selidx_g[b * Mm + tid] = selidx[tid];
}

// ---------------- offset MLP for one row (full unroll, bit-identical math) ----------------
__device__ __forceinline__ void off_mlp_row(
    long row, const float* __restrict__ cand, const float* basev,
    const float* __restrict__ o_w1, const float* __restrict__ o_g1, const float* __restrict__ o_be1,
    const float* __restrict__ o_w2, const float* __restrict__ o_b2,
    const float* __restrict__ o_g2, const float* __restrict__ o_be2,
    const float* __restrict__ o_w3, const float* __restrict__ o_b3,
    float& o0, float& o1)
{
    float cx = cand[row * 2 + 0];
    float cy = cand[row * 2 + 1];
    const float* u = o_w1 + 128 * Hh;
    const float* v = o_w1 + 129 * Hh;
    float a[Hh];
    float sum = 0.f, sq = 0.f;
    #pragma unroll
    for (int j = 0; j < Hh; ++j) {
        float t = fmaf(cy, v[j], fmaf(cx, u[j], basev[j]));
        a[j] = t;
        sum += t;
        sq = fmaf(t, t, sq);
    }
    float mu = sum * (1.f / Hh);
    float rstd = rsqrtf(sq * (1.f / Hh) - mu * mu + 1e-5f);
    #pragma unroll
    for (int j = 0; j < Hh; ++j)
        a[j] = fmaxf(fmaf((a[j] - mu) * rstd, o_g1[j], o_be1[j]), 0.f);
    float h[Hh];
    #pragma unroll
    for (int i = 0; i < Hh; ++i) h[i] = 0.f;
    #pragma unroll
    for (int j = 0; j < Hh; ++j) {
        float av = a[j];
        const float* w2r = o_w2 + j * Hh;
        #pragma unroll
        for (int i = 0; i < Hh; ++i) h[i] = fmaf(av, w2r[i], h[i]);
    }
    float sum2 = 0.f, sq2 = 0.f;
    #pragma unroll
    for (int i = 0; i < Hh; ++i) {
        float hv = h[i] + o_b2[i];
        h[i] = hv;
        sum2 += hv;
        sq2 = fmaf(hv, hv, sq2);
    }
    float mu2 = sum2 * (1.f / Hh);
    float rstd2 = rsqrtf(sq2 * (1.f / Hh) - mu2 * mu2 + 1e-5f);
    o0 = o_b3[0]; o1 = o_b3[1];
    #pragma unroll
    for (int i = 0; i < Hh; ++i) {
        float aa = fmaxf(fmaf((h[i] - mu2) * rstd2, o_g2[i], o_be2[i]), 0.f);
        o0 = fmaf(aa, o_w3[i * 2 + 0], o0);
        o1 = fmaf(aa, o_w3[i * 2 + 1], o1);
    }
}

// ---------------- K4: offset MLP on 51 rows/batch + gather + NMS + SL1 ----------------
__global__ __launch_bounds__(64, 1) void k_off(
    const float* __restrict__ cand, const float* __restrict__ feat,
    const int* __restrict__ selidx_g, const int* __restrict__ gidx_g,
    const float* __restrict__ off_gt,
    const float* __restrict__ o_w1, const float* __restrict__ o_b1,
    const float* __restrict__ o_g1, const float* __restrict__ o_be1,
    const float* __restrict__ o_w2, const float* __restrict__ o_b2,
    const float* __restrict__ o_g2, const float* __restrict__ o_be2,
    const float* __restrict__ o_w3, const float* __restrict__ o_b3,
    float* __restrict__ out, float* __restrict__ sl1_part)
{
    __shared__ float base_s[Hh];
    __shared__ float tx[Mm], ty[Mm];
    int b = blockIdx.x, tid = threadIdx.x;

    {
        const float* f = feat + b * Cc;
        float s = o_b1[tid];
        #pragma unroll 8
        for (int c = 0; c < Cc; ++c) s = fmaf(f[c], o_w1[c * Hh + tid], s);
        base_s[tid] = s;
    }
    __syncthreads();

    int idx;
    if (tid < Mm)        idx = selidx_g[b * Mm + tid];
    else if (tid == Mm)  idx = gidx_g[b];
    else                 idx = 0;
    long row = (long)b * Nn + idx;

    float o0, o1;
    off_mlp_row(row, cand, base_s, o_w1, o_g1, o_be1, o_w2, o_b2, o_g2, o_be2, o_w3, o_b3, o0, o1);

    if (tid < Mm) {
        tx[tid] = cand[row * 2 + 0] + o0;
        ty[tid] = cand[row * 2 + 1] + o1;
    } else if (tid == Mm) {
        float s1 = 0.f;
        float d0 = o0 - off_gt[b * 2 + 0];
        float ad0 = fabsf(d0);
        s1 += (ad0 < 1.f) ? 0.5f * d0 * d0 : ad0 - 0.5f;
        float d1 = o1 - off_gt[b * 2 + 1];
        float ad1 = fabsf(d1);
        s1 += (ad1 < 1.f) ? 0.5f * d1 * d1 : ad1 - 0.5f;
        sl1_part[b] = s1;
    }
    __syncthreads();
    if (tid == 0) {
        float sx[6], sy[6];
        #pragma unroll
        for (int k = 0; k < 6; ++k) { sx[k] = tx[k]; sy[k] = ty[k]; }
        int cnt = 1;
        for (int i = 1; i < Mm; ++i) {
            bool close = false;
            #pragma unroll
            for (int k = 0; k < 6; ++k) {
                float dx = sx[k] - tx[i], dy = sy[k] - ty[i];
                close = close || ((k < cnt) && (dx * dx + dy * dy < 2.0f));
            }
            if (!close && cnt < 6) { sx[cnt] = tx[i]; sy[cnt] = ty[i]; cnt++; }
        }
        #pragma unroll
        for (int k = 0; k < 6; ++k) {
            out[(b * 6 + k) * 2 + 0] = sx[k];
            out[(b * 6 + k) * 2 + 1] = sy[k];
        }
    }
}

// ---------------- K5: final loss (parallel) ----------------
__global__ __launch_bounds__(256) void k_loss(const float* __restrict__ bce_part,
                                              const float* __restrict__ sl1_part,
                                              float* __restrict__ out) {
    __shared__ float redb[4], reds[4];
    int tid = threadIdx.x, wave = tid >> 6, lane = tid & 63;
    float sb = bce_part[tid];
    float ss = sl1_part[tid];
    #pragma unroll
    for (int mm = 1; mm < 64; mm <<= 1) { sb += __shfl_xor(sb, mm); ss += __shfl_xor(ss, mm); }
    if (lane == 0) { redb[wave] = sb; reds[wave] = ss; }
    __syncthreads();
    if (tid == 0) {
        float tb = ((redb[0] + redb[1]) + redb[2]) + redb[3];
        float ts = ((reds[0] + reds[1]) + reds[2]) + reds[3];
        out[0] = -tb / (float)(Bb * Nn) + ts / (float)(Bb * 2);
    }
}

extern "C" void kernel_launch(void* const* d_in, const int* in_sizes, int n_in,
                              void* d_out, int out_size, void* d_ws, size_t ws_size,
                              hipStream_t stream) {
    const float* feat  = (const float*)d_in[0];
    const float* cand  = (const float*)d_in[1];
    const float* mask  = (const float*)d_in[2];
    const float* gt    = (const float*)d_in[3];
    const float* ogt   = (const float*)d_in[4];
    const float* p_w1  = (const float*)d_in[5];
    const float* p_b1  = (const float*)d_in[6];
    const float* p_g1  = (const float*)d_in[7];
    const float* p_be1 = (const float*)d_in[8];
    const float* p_w2  = (const float*)d_in[9];
    const float* p_b2  = (const float*)d_in[10];
    const float* p_g2  = (const float*)d_in[11];
    const float* p_be2 = (const float*)d_in[12];
    const float* p_w3  = (const float*)d_in[13];
    const float* p_b3  = (const float*)d_in[14];
    const float* o_w1  = (const float*)d_in[15];
    const float* o_b1  = (const float*)d_in[16];
    const float* o_g1  = (const float*)d_in[17];
    const float* o_be1 = (const float*)d_in[18];
    const float* o_w2  = (const float*)d_in[19];
    const float* o_g2  = (const float*)d_in[20];   // NOTE: dict order puts o_g2 before o_b2
    const float* o_b2  = (const float*)d_in[21];
    const float* o_be2 = (const float*)d_in[22];
    const float* o_w3  = (const float*)d_in[23];
    const float* o_b3  = (const float*)d_in[24];

    float* ws       = (float*)d_ws;
    float* logits   = ws;                        // B*N
    float* bce_part = logits + (long)Bb * Nn;    // B
    float* sl1_part = bce_part + Bb;             // B
    int*   selidx_g = (int*)(sl1_part + Bb);     // B*M ints
    int*   gidx_g   = selidx_g + Bb * Mm;        // B ints

    float* out = (float*)d_out;                  // (B,6,2) floats then loss scalar

    k_mlp_p<<<Bb * 32, 256, 0, stream>>>(feat, cand,
        p_w1, p_b1, p_g1, p_be1, p_w2, p_b2, p_g2, p_be2, p_w3, p_b3, logits);
    k_post<<<Bb, 256, 0, stream>>>(logits, mask, gt, bce_part, selidx_g, gidx_g);
    k_off<<<Bb, 64, 0, stream>>>(cand, feat, selidx_g, gidx_g, ogt,
        o_w1, o_b1, o_g1, o_be1, o_w2, o_b2, o_g2, o_be2, o_w3, o_b3, out, sl1_part);
    k_loss<<<1, 256, 0, stream>>>(bce_part, sl1_part, out + Bb * 6 * 2);
}

// Round 10
// 212.257 us; speedup vs baseline: 1.6129x; 1.6129x over previous
//
#include <hip/hip_runtime.h>
#include <hip/hip_bf16.h>
#include <math.h>

#define Bb 256
#define Nn 2048
#define Cc 128
#define Hh 64
#define Mm 50

// ---------------- K1: per-batch feat @ W1[:128] + b1 for BOTH MLPs ----------------
__global__ __launch_bounds__(128) void k_base(const float* __restrict__ feat,
                                              const float* __restrict__ p_w1,
                                              const float* __restrict__ p_b1,
                                              const float* __restrict__ o_w1,
                                              const float* __restrict__ o_b1,
                                              float* __restrict__ basep,
                                              float* __restrict__ baseo) {
    int b = blockIdx.x, tid = threadIdx.x;
    int k = tid & 63;
    bool lo = tid < 64;                     // wave-uniform select
    const float* w1 = lo ? p_w1 : o_w1;
    const float* b1 = lo ? p_b1 : o_b1;
    float* dst = lo ? basep : baseo;
    const float* f = feat + b * Cc;
    float s = b1[k];
    #pragma unroll 8
    for (int c = 0; c < Cc; ++c) s = fmaf(f[c], w1[c * Hh + k], s);
    dst[b * Hh + k] = s;
}

// ---------------- K2: prob MLP, 2 rows/thread, full unroll, NO LDS (R5-proven, amortized) ----
__global__ __launch_bounds__(256, 1) void k_mlp_p(
    const float* __restrict__ cand, const float* __restrict__ basep,
    const float* __restrict__ p_w1, const float* __restrict__ p_g1, const float* __restrict__ p_be1,
    const float* __restrict__ p_w2, const float* __restrict__ p_b2,
    const float* __restrict__ p_g2, const float* __restrict__ p_be2,
    const float* __restrict__ p_w3, const float* __restrict__ p_b3,
    float* __restrict__ logits)
{
    int tid = threadIdx.x;
    int b = blockIdx.x >> 2;                 // 4 blocks x 512 rows = 2048 rows/batch
    int n0 = ((blockIdx.x & 3) << 9) + tid;  // rows n0 and n0+256
    long row0 = (long)b * Nn + n0;
    long row1 = row0 + 256;
    float2 cA = ((const float2*)cand)[row0];
    float2 cB = ((const float2*)cand)[row1];
    const float* basev = basep + b * Hh;
    const float* u = p_w1 + 128 * Hh;
    const float* v = p_w1 + 129 * Hh;

    // ---- layer-1 LN stats, both rows (weights loaded once, shared) ----
    float sumA = 0.f, sqA = 0.f, sumB = 0.f, sqB = 0.f;
    #pragma unroll
    for (int j = 0; j < Hh; ++j) {
        float uj = u[j], vj = v[j], bj = basev[j];
        float tA = fmaf(cA.y, vj, fmaf(cA.x, uj, bj));
        float tB = fmaf(cB.y, vj, fmaf(cB.x, uj, bj));
        sumA += tA; sqA = fmaf(tA, tA, sqA);
        sumB += tB; sqB = fmaf(tB, tB, sqB);
    }
    float muA = sumA * (1.f / Hh);
    float rstdA = rsqrtf(sqA * (1.f / Hh) - muA * muA + 1e-5f);
    float muB = sumB * (1.f / Hh);
    float rstdB = rsqrtf(sqB * (1.f / Hh) - muB * muB + 1e-5f);

    // ---- layer 2, h0/h1 accumulators; a recomputed inline (2 FMA + LN per use) ----
    float h0[Hh], h1[Hh];
    #pragma unroll
    for (int i = 0; i < Hh; ++i) { h0[i] = 0.f; h1[i] = 0.f; }
    #pragma unroll
    for (int j = 0; j < Hh; ++j) {
        float uj = u[j], vj = v[j], bj = basev[j];
        float g = p_g1[j], be = p_be1[j];
        float tA = fmaf(cA.y, vj, fmaf(cA.x, uj, bj));
        float aA = fmaxf(fmaf((tA - muA) * rstdA, g, be), 0.f);
        float tB = fmaf(cB.y, vj, fmaf(cB.x, uj, bj));
        float aB = fmaxf(fmaf((tB - muB) * rstdB, g, be), 0.f);
        const float* w2r = p_w2 + j * Hh;
        #pragma unroll
        for (int i = 0; i < Hh; ++i) {
            float w = w2r[i];
            h0[i] = fmaf(aA, w, h0[i]);
            h1[i] = fmaf(aB, w, h1[i]);
        }
    }

    // ---- bias + LN2 stats (reference order per row) ----
    float sum2A = 0.f, sq2A = 0.f, sum2B = 0.f, sq2B = 0.f;
    #pragma unroll
    for (int i = 0; i < Hh; ++i) {
        float b2 = p_b2[i];
        float hA = h0[i] + b2; h0[i] = hA; sum2A += hA; sq2A = fmaf(hA, hA, sq2A);
        float hB = h1[i] + b2; h1[i] = hB; sum2B += hB; sq2B = fmaf(hB, hB, sq2B);
    }
    float mu2A = sum2A * (1.f / Hh);
    float rstd2A = rsqrtf(sq2A * (1.f / Hh) - mu2A * mu2A + 1e-5f);
    float mu2B = sum2B * (1.f / Hh);
    float rstd2B = rsqrtf(sq2B * (1.f / Hh) - mu2B * mu2B + 1e-5f);

    // ---- head ----
    float b3 = p_b3[0];
    float lgA = b3, lgB = b3;
    #pragma unroll
    for (int i = 0; i < Hh; ++i) {
        float g2 = p_g2[i], be2 = p_be2[i], w3 = p_w3[i];
        float aA = fmaxf(fmaf((h0[i] - mu2A) * rstd2A, g2, be2), 0.f);
        lgA = fmaf(aA, w3, lgA);
        float aB = fmaxf(fmaf((h1[i] - mu2B) * rstd2B, g2, be2), 0.f);
        lgB = fmaf(aB, w3, lgB);
    }
    logits[row0] = lgA;
    logits[row1] = lgB;
}

// ---------------- K3: wave-per-batch softmax + BCE + top-50 (barrier-free) ----------------
__global__ __launch_bounds__(256) void k_post(
    const float* __restrict__ logits, const float* __restrict__ mask,
    const float* __restrict__ gt,
    float* __restrict__ bce_part, int* __restrict__ selidx_g, int* __restrict__ gidx_g)
{
    __shared__ float vals[4][Nn];           // 32 KB, one row per wave
    int wave = threadIdx.x >> 6, lane = threadIdx.x & 63;
    int b = blockIdx.x * 4 + wave;
    const float* lg = logits + (long)b * Nn;
    const float* mk = mask + (long)b * Nn;
    const float* g  = gt + (long)b * Nn;
    float* vw = vals[wave];

    // ---- max (exact, order-independent) ----
    float xv[32];
    float mx = -1e30f;
    #pragma unroll
    for (int k = 0; k < 32; ++k) {
        int n = lane + k * 64;
        xv[k] = lg[n] + mk[n];
        mx = fmaxf(mx, xv[k]);
    }
    #pragma unroll
    for (int m = 1; m < 64; m <<= 1) mx = fmaxf(mx, __shfl_xor(mx, m));

    // ---- exp + sum (Z order differs from ref; p = e*invZ order-preserving) ----
    float ev[32]; float es = 0.f;
    #pragma unroll
    for (int k = 0; k < 32; ++k) { ev[k] = expf(xv[k] - mx); es += ev[k]; }
    #pragma unroll
    for (int m = 1; m < 64; m <<= 1) es += __shfl_xor(es, m);
    float invZ = 1.f / es;

    // ---- p, BCE partial, gt index ----
    float bs = 0.f; int gidx = 0x7fffffff;
    #pragma unroll
    for (int k = 0; k < 32; ++k) {
        int n = lane + k * 64;
        float pv = ev[k] * invZ;
        vw[n] = pv;
        float gv = g[n];
        float lp = fmaxf(logf(pv), -100.f);
        float l1p = fmaxf(log1pf(-pv), -100.f);
        bs += gv * lp + (1.f - gv) * l1p;
        if (gv > 0.5f) gidx = min(gidx, n);
    }
    #pragma unroll
    for (int m = 1; m < 64; m <<= 1) {
        bs += __shfl_xor(bs, m);
        gidx = min(gidx, __shfl_xor(gidx, m));
    }
    if (lane == 0) { bce_part[b] = bs; gidx_g[b] = gidx; }

    // ---- top-50 (exact lax.top_k order: desc value, asc index on ties) ----
    float bv = -1.f; int bi = 0x7fffffff;
    #pragma unroll
    for (int k = 0; k < 32; ++k) {          // ascending n per lane -> min idx on ties
        int n = lane + k * 64;
        float vv = vw[n];
        if (vv > bv) { bv = vv; bi = n; }
    }
    for (int it = 0; it < Mm; ++it) {
        float rv = bv; int ri = bi;
        #pragma unroll
        for (int m = 1; m < 64; m <<= 1) {
            float v2 = __shfl_xor(rv, m); int i2 = __shfl_xor(ri, m);
            if (v2 > rv || (v2 == rv && i2 < ri)) { rv = v2; ri = i2; }
        }
        if (lane == 0) selidx_g[b * Mm + it] = ri;
        if ((ri & 63) == lane) {            // owner lane: remove + rescan its 32
            vw[ri] = -1.f;
            bv = -1.f; bi = 0x7fffffff;
            #pragma unroll
            for (int k = 0; k < 32; ++k) {
                int n = lane + k * 64;
                float vv = vw[n];
                if (vv > bv) { bv = vv; bi = n; }
            }
        }
    }
}

// ---------------- offset MLP for one row (full unroll, bit-identical math) ----------------
__device__ __forceinline__ void off_mlp_row(
    long row, const float* __restrict__ cand, const float* basev,
    const float* __restrict__ o_w1, const float* __restrict__ o_g1, const float* __restrict__ o_be1,
    const float* __restrict__ o_w2, const float* __restrict__ o_b2,
    const float* __restrict__ o_g2, const float* __restrict__ o_be2,
    const float* __restrict__ o_w3, const float* __restrict__ o_b3,
    float& o0, float& o1)
{
    float cx = cand[row * 2 + 0];
    float cy = cand[row * 2 + 1];
    const float* u = o_w1 + 128 * Hh;
    const float* v = o_w1 + 129 * Hh;
    float a[Hh];
    float sum = 0.f, sq = 0.f;
    #pragma unroll
    for (int j = 0; j < Hh; ++j) {
        float t = fmaf(cy, v[j], fmaf(cx, u[j], basev[j]));
        a[j] = t;
        sum += t;
        sq = fmaf(t, t, sq);
    }
    float mu = sum * (1.f / Hh);
    float rstd = rsqrtf(sq * (1.f / Hh) - mu * mu + 1e-5f);
    #pragma unroll
    for (int j = 0; j < Hh; ++j)
        a[j] = fmaxf(fmaf((a[j] - mu) * rstd, o_g1[j], o_be1[j]), 0.f);
    float h[Hh];
    #pragma unroll
    for (int i = 0; i < Hh; ++i) h[i] = 0.f;
    #pragma unroll
    for (int j = 0; j < Hh; ++j) {
        float av = a[j];
        const float* w2r = o_w2 + j * Hh;
        #pragma unroll
        for (int i = 0; i < Hh; ++i) h[i] = fmaf(av, w2r[i], h[i]);
    }
    float sum2 = 0.f, sq2 = 0.f;
    #pragma unroll
    for (int i = 0; i < Hh; ++i) {
        float hv = h[i] + o_b2[i];
        h[i] = hv;
        sum2 += hv;
        sq2 = fmaf(hv, hv, sq2);
    }
    float mu2 = sum2 * (1.f / Hh);
    float rstd2 = rsqrtf(sq2 * (1.f / Hh) - mu2 * mu2 + 1e-5f);
    o0 = o_b3[0]; o1 = o_b3[1];
    #pragma unroll
    for (int i = 0; i < Hh; ++i) {
        float aa = fmaxf(fmaf((h[i] - mu2) * rstd2, o_g2[i], o_be2[i]), 0.f);
        o0 = fmaf(aa, o_w3[i * 2 + 0], o0);
        o1 = fmaf(aa, o_w3[i * 2 + 1], o1);
    }
}

// ---------------- K4: offset MLP on 51 rows/batch + gather + NMS + SL1 ----------------
__global__ __launch_bounds__(64, 1) void k_off(
    const float* __restrict__ cand, const float* __restrict__ baseo,
    const int* __restrict__ selidx_g, const int* __restrict__ gidx_g,
    const float* __restrict__ off_gt,
    const float* __restrict__ o_w1, const float* __restrict__ o_g1, const float* __restrict__ o_be1,
    const float* __restrict__ o_w2, const float* __restrict__ o_b2,
    const float* __restrict__ o_g2, const float* __restrict__ o_be2,
    const float* __restrict__ o_w3, const float* __restrict__ o_b3,
    float* __restrict__ out, float* __restrict__ sl1_part)
{
    __shared__ float tx[Mm], ty[Mm];
    int b = blockIdx.x, tid = threadIdx.x;
    const float* basev = baseo + b * Hh;

    int idx;
    if (tid < Mm)        idx = selidx_g[b * Mm + tid];
    else if (tid == Mm)  idx = gidx_g[b];
    else                 idx = 0;
    long row = (long)b * Nn + idx;

    float o0, o1;
    off_mlp_row(row, cand, basev, o_w1, o_g1, o_be1, o_w2, o_b2, o_g2, o_be2, o_w3, o_b3, o0, o1);

    if (tid < Mm) {
        tx[tid] = cand[row * 2 + 0] + o0;
        ty[tid] = cand[row * 2 + 1] + o1;
    } else if (tid == Mm) {
        float s1 = 0.f;
        float d0 = o0 - off_gt[b * 2 + 0];
        float ad0 = fabsf(d0);
        s1 += (ad0 < 1.f) ? 0.5f * d0 * d0 : ad0 - 0.5f;
        float d1 = o1 - off_gt[b * 2 + 1];
        float ad1 = fabsf(d1);
        s1 += (ad1 < 1.f) ? 0.5f * d1 * d1 : ad1 - 0.5f;
        sl1_part[b] = s1;
    }
    __syncthreads();
    if (tid == 0) {
        float sx[6], sy[6];
        #pragma unroll
        for (int k = 0; k < 6; ++k) { sx[k] = tx[k]; sy[k] = ty[k]; }
        int cnt = 1;
        for (int i = 1; i < Mm; ++i) {
            bool close = false;
            #pragma unroll
            for (int k = 0; k < 6; ++k) {
                float dx = sx[k] - tx[i], dy = sy[k] - ty[i];
                close = close || ((k < cnt) && (dx * dx + dy * dy < 2.0f));
            }
            if (!close && cnt < 6) { sx[cnt] = tx[i]; sy[cnt] = ty[i]; cnt++; }
        }
        #pragma unroll
        for (int k = 0; k < 6; ++k) {
            out[(b * 6 + k) * 2 + 0] = sx[k];
            out[(b * 6 + k) * 2 + 1] = sy[k];
        }
    }
}

// ---------------- K5: final loss (parallel) ----------------
__global__ __launch_bounds__(256) void k_loss(const float* __restrict__ bce_part,
                                              const float* __restrict__ sl1_part,
                                              float* __restrict__ out) {
    __shared__ float redb[4], reds[4];
    int tid = threadIdx.x, wave = tid >> 6, lane = tid & 63;
    float sb = bce_part[tid];
    float ss = sl1_part[tid];
    #pragma unroll
    for (int mm = 1; mm < 64; mm <<= 1) { sb += __shfl_xor(sb, mm); ss += __shfl_xor(ss, mm); }
    if (lane == 0) { redb[wave] = sb; reds[wave] = ss; }
    __syncthreads();
    if (tid == 0) {
        float tb = ((redb[0] + redb[1]) + redb[2]) + redb[3];
        float ts = ((reds[0] + reds[1]) + reds[2]) + reds[3];
        out[0] = -tb / (float)(Bb * Nn) + ts / (float)(Bb * 2);
    }
}

extern "C" void kernel_launch(void* const* d_in, const int* in_sizes, int n_in,
                              void* d_out, int out_size, void* d_ws, size_t ws_size,
                              hipStream_t stream) {
    const float* feat  = (const float*)d_in[0];
    const float* cand  = (const float*)d_in[1];
    const float* mask  = (const float*)d_in[2];
    const float* gt    = (const float*)d_in[3];
    const float* ogt   = (const float*)d_in[4];
    const float* p_w1  = (const float*)d_in[5];
    const float* p_b1  = (const float*)d_in[6];
    const float* p_g1  = (const float*)d_in[7];
    const float* p_be1 = (const float*)d_in[8];
    const float* p_w2  = (const float*)d_in[9];
    const float* p_b2  = (const float*)d_in[10];
    const float* p_g2  = (const float*)d_in[11];
    const float* p_be2 = (const float*)d_in[12];
    const float* p_w3  = (const float*)d_in[13];
    const float* p_b3  = (const float*)d_in[14];
    const float* o_w1  = (const float*)d_in[15];
    const float* o_b1  = (const float*)d_in[16];
    const float* o_g1  = (const float*)d_in[17];
    const float* o_be1 = (const float*)d_in[18];
    const float* o_w2  = (const float*)d_in[19];
    const float* o_g2  = (const float*)d_in[20];   // NOTE: dict order puts o_g2 before o_b2
    const float* o_b2  = (const float*)d_in[21];
    const float* o_be2 = (const float*)d_in[22];
    const float* o_w3  = (const float*)d_in[23];
    const float* o_b3  = (const float*)d_in[24];

    float* ws       = (float*)d_ws;
    float* basep    = ws;                        // B*H
    float* baseo    = basep + Bb * Hh;           // B*H
    float* logits   = baseo + Bb * Hh;           // B*N
    float* bce_part = logits + (long)Bb * Nn;    // B
    float* sl1_part = bce_part + Bb;             // B
    int*   selidx_g = (int*)(sl1_part + Bb);     // B*M ints
    int*   gidx_g   = selidx_g + Bb * Mm;        // B ints

    float* out = (float*)d_out;                  // (B,6,2) floats then loss scalar

    k_base<<<Bb, 128, 0, stream>>>(feat, p_w1, p_b1, o_w1, o_b1, basep, baseo);
    k_mlp_p<<<Bb * 4, 256, 0, stream>>>(cand, basep,
        p_w1, p_g1, p_be1, p_w2, p_b2, p_g2, p_be2, p_w3, p_b3, logits);
    k_post<<<Bb / 4, 256, 0, stream>>>(logits, mask, gt, bce_part, selidx_g, gidx_g);
    k_off<<<Bb, 64, 0, stream>>>(cand, baseo, selidx_g, gidx_g, ogt,
        o_w1, o_g1, o_be1, o_w2, o_b2, o_g2, o_be2, o_w3, o_b3, out, sl1_part);
    k_loss<<<1, 256, 0, stream>>>(bce_part, sl1_part, out + Bb * 6 * 2);
}

// Round 11
// 171.348 us; speedup vs baseline: 1.9980x; 1.2388x over previous
//
#include <hip/hip_runtime.h>
#include <hip/hip_bf16.h>
#include <math.h>

#define Bb 256
#define Nn 2048
#define Cc 128
#define Hh 64
#define Mm 50

// ---------------- K1: per-batch feat @ W1[:128] + b1 for BOTH MLPs ----------------
__global__ __launch_bounds__(128) void k_base(const float* __restrict__ feat,
                                              const float* __restrict__ p_w1,
                                              const float* __restrict__ p_b1,
                                              const float* __restrict__ o_w1,
                                              const float* __restrict__ o_b1,
                                              float* __restrict__ basep,
                                              float* __restrict__ baseo) {
    int b = blockIdx.x, tid = threadIdx.x;
    int k = tid & 63;
    bool lo = tid < 64;                     // wave-uniform select
    const float* w1 = lo ? p_w1 : o_w1;
    const float* b1 = lo ? p_b1 : o_b1;
    float* dst = lo ? basep : baseo;
    const float* f = feat + b * Cc;
    float s = b1[k];
    #pragma unroll 8
    for (int c = 0; c < Cc; ++c) s = fmaf(f[c], w1[c * Hh + k], s);
    dst[b * Hh + k] = s;
}

// ---------------- K2: prob MLP, thread-per-row, ROLLED j-loops, small code ----------------
// No a[] array (rematerialized from wave-uniform scalars). h[64] literal-indexed only,
// written inside a rolled loop -> compiler must keep it register-resident (R6 evidence).
__global__ __launch_bounds__(256, 1) void k_mlp_p(
    const float* __restrict__ cand, const float* __restrict__ basep,
    const float* __restrict__ p_w1, const float* __restrict__ p_g1, const float* __restrict__ p_be1,
    const float* __restrict__ p_w2, const float* __restrict__ p_b2,
    const float* __restrict__ p_g2, const float* __restrict__ p_be2,
    const float* __restrict__ p_w3, const float* __restrict__ p_b3,
    float* __restrict__ logits)
{
    int tid = threadIdx.x;
    int b = blockIdx.x >> 3;                 // 8 blocks x 256 threads = 2048 rows/batch
    int n = ((blockIdx.x & 7) << 8) + tid;
    long row = (long)b * Nn + n;
    float2 c2 = ((const float2*)cand)[row];
    float cx = c2.x, cy = c2.y;
    const float* basev = basep + b * Hh;
    const float* u = p_w1 + 128 * Hh;
    const float* v = p_w1 + 129 * Hh;

    // ---- LN1 stats: rolled, exact sequential j order ----
    float sum = 0.f, sq = 0.f;
    #pragma unroll 1
    for (int j = 0; j < Hh; ++j) {
        float t = fmaf(cy, v[j], fmaf(cx, u[j], basev[j]));
        sum += t;
        sq = fmaf(t, t, sq);
    }
    float mu = sum * (1.f / Hh);
    float rstd = rsqrtf(sq * (1.f / Hh) - mu * mu + 1e-5f);

    // ---- layer 2: rolled j, a_j rematerialized (5 ops), 64 literal-index FMAs ----
    float h[Hh];
    #pragma unroll
    for (int i = 0; i < Hh; ++i) h[i] = 0.f;
    #pragma unroll 1
    for (int j = 0; j < Hh; ++j) {
        float t = fmaf(cy, v[j], fmaf(cx, u[j], basev[j]));
        float a = fmaxf(fmaf((t - mu) * rstd, p_g1[j], p_be1[j]), 0.f);
        const float* w2r = p_w2 + j * Hh;
        #pragma unroll
        for (int i = 0; i < Hh; ++i) h[i] = fmaf(a, w2r[i], h[i]);
    }

    // ---- bias + LN2 stats (reference order) ----
    float sum2 = 0.f, sq2 = 0.f;
    #pragma unroll
    for (int i = 0; i < Hh; ++i) {
        float hv = h[i] + p_b2[i];
        h[i] = hv;
        sum2 += hv;
        sq2 = fmaf(hv, hv, sq2);
    }
    float mu2 = sum2 * (1.f / Hh);
    float rstd2 = rsqrtf(sq2 * (1.f / Hh) - mu2 * mu2 + 1e-5f);

    // ---- head ----
    float lg = p_b3[0];
    #pragma unroll
    for (int i = 0; i < Hh; ++i) {
        float aa = fmaxf(fmaf((h[i] - mu2) * rstd2, p_g2[i], p_be2[i]), 0.f);
        lg = fmaf(aa, p_w3[i], lg);
    }
    logits[row] = lg;
}

// ---------------- K3: wave-per-batch softmax + BCE + top-50 (barrier-free) ----------------
__global__ __launch_bounds__(256) void k_post(
    const float* __restrict__ logits, const float* __restrict__ mask,
    const float* __restrict__ gt,
    float* __restrict__ bce_part, int* __restrict__ selidx_g, int* __restrict__ gidx_g)
{
    __shared__ float vals[4][Nn];           // 32 KB, one row per wave
    int wave = threadIdx.x >> 6, lane = threadIdx.x & 63;
    int b = blockIdx.x * 4 + wave;
    const float* lg = logits + (long)b * Nn;
    const float* mk = mask + (long)b * Nn;
    const float* g  = gt + (long)b * Nn;
    float* vw = vals[wave];

    // ---- max (exact, order-independent) ----
    float xv[32];
    float mx = -1e30f;
    #pragma unroll
    for (int k = 0; k < 32; ++k) {
        int n = lane + k * 64;
        xv[k] = lg[n] + mk[n];
        mx = fmaxf(mx, xv[k]);
    }
    #pragma unroll
    for (int m = 1; m < 64; m <<= 1) mx = fmaxf(mx, __shfl_xor(mx, m));

    // ---- exp + sum (Z order differs from ref; p = e*invZ order-preserving) ----
    float ev[32]; float es = 0.f;
    #pragma unroll
    for (int k = 0; k < 32; ++k) { ev[k] = expf(xv[k] - mx); es += ev[k]; }
    #pragma unroll
    for (int m = 1; m < 64; m <<= 1) es += __shfl_xor(es, m);
    float invZ = 1.f / es;

    // ---- p, BCE partial, gt index ----
    float bs = 0.f; int gidx = 0x7fffffff;
    #pragma unroll
    for (int k = 0; k < 32; ++k) {
        int n = lane + k * 64;
        float pv = ev[k] * invZ;
        vw[n] = pv;
        float gv = g[n];
        float lp = fmaxf(logf(pv), -100.f);
        float l1p = fmaxf(log1pf(-pv), -100.f);
        bs += gv * lp + (1.f - gv) * l1p;
        if (gv > 0.5f) gidx = min(gidx, n);
    }
    #pragma unroll
    for (int m = 1; m < 64; m <<= 1) {
        bs += __shfl_xor(bs, m);
        gidx = min(gidx, __shfl_xor(gidx, m));
    }
    if (lane == 0) { bce_part[b] = bs; gidx_g[b] = gidx; }

    // ---- top-50 (exact lax.top_k order: desc value, asc index on ties) ----
    float bv = -1.f; int bi = 0x7fffffff;
    #pragma unroll
    for (int k = 0; k < 32; ++k) {          // ascending n per lane -> min idx on ties
        int n = lane + k * 64;
        float vv = vw[n];
        if (vv > bv) { bv = vv; bi = n; }
    }
    for (int it = 0; it < Mm; ++it) {
        float rv = bv; int ri = bi;
        #pragma unroll
        for (int m = 1; m < 64; m <<= 1) {
            float v2 = __shfl_xor(rv, m); int i2 = __shfl_xor(ri, m);
            if (v2 > rv || (v2 == rv && i2 < ri)) { rv = v2; ri = i2; }
        }
        if (lane == 0) selidx_g[b * Mm + it] = ri;
        if ((ri & 63) == lane) {            // owner lane: remove + rescan its 32
            vw[ri] = -1.f;
            bv = -1.f; bi = 0x7fffffff;
            #pragma unroll
            for (int k = 0; k < 32; ++k) {
                int n = lane + k * 64;
                float vv = vw[n];
                if (vv > bv) { bv = vv; bi = n; }
            }
        }
    }
}

// ---------------- offset MLP for one row (full unroll, bit-identical math) ----------------
__device__ __forceinline__ void off_mlp_row(
    long row, const float* __restrict__ cand, const float* basev,
    const float* __restrict__ o_w1, const float* __restrict__ o_g1, const float* __restrict__ o_be1,
    const float* __restrict__ o_w2, const float* __restrict__ o_b2,
    const float* __restrict__ o_g2, const float* __restrict__ o_be2,
    const float* __restrict__ o_w3, const float* __restrict__ o_b3,
    float& o0, float& o1)
{
    float cx = cand[row * 2 + 0];
    float cy = cand[row * 2 + 1];
    const float* u = o_w1 + 128 * Hh;
    const float* v = o_w1 + 129 * Hh;
    float a[Hh];
    float sum = 0.f, sq = 0.f;
    #pragma unroll
    for (int j = 0; j < Hh; ++j) {
        float t = fmaf(cy, v[j], fmaf(cx, u[j], basev[j]));
        a[j] = t;
        sum += t;
        sq = fmaf(t, t, sq);
    }
    float mu = sum * (1.f / Hh);
    float rstd = rsqrtf(sq * (1.f / Hh) - mu * mu + 1e-5f);
    #pragma unroll
    for (int j = 0; j < Hh; ++j)
        a[j] = fmaxf(fmaf((a[j] - mu) * rstd, o_g1[j], o_be1[j]), 0.f);
    float h[Hh];
    #pragma unroll
    for (int i = 0; i < Hh; ++i) h[i] = 0.f;
    #pragma unroll
    for (int j = 0; j < Hh; ++j) {
        float av = a[j];
        const float* w2r = o_w2 + j * Hh;
        #pragma unroll
        for (int i = 0; i < Hh; ++i) h[i] = fmaf(av, w2r[i], h[i]);
    }
    float sum2 = 0.f, sq2 = 0.f;
    #pragma unroll
    for (int i = 0; i < Hh; ++i) {
        float hv = h[i] + o_b2[i];
        h[i] = hv;
        sum2 += hv;
        sq2 = fmaf(hv, hv, sq2);
    }
    float mu2 = sum2 * (1.f / Hh);
    float rstd2 = rsqrtf(sq2 * (1.f / Hh) - mu2 * mu2 + 1e-5f);
    o0 = o_b3[0]; o1 = o_b3[1];
    #pragma unroll
    for (int i = 0; i < Hh; ++i) {
        float aa = fmaxf(fmaf((h[i] - mu2) * rstd2, o_g2[i], o_be2[i]), 0.f);
        o0 = fmaf(aa, o_w3[i * 2 + 0], o0);
        o1 = fmaf(aa, o_w3[i * 2 + 1], o1);
    }
}

// ---------------- K4: offset MLP on 51 rows/batch + gather + NMS + SL1 ----------------
__global__ __launch_bounds__(64, 1) void k_off(
    const float* __restrict__ cand, const float* __restrict__ baseo,
    const int* __restrict__ selidx_g, const int* __restrict__ gidx_g,
    const float* __restrict__ off_gt,
    const float* __restrict__ o_w1, const float* __restrict__ o_g1, const float* __restrict__ o_be1,
    const float* __restrict__ o_w2, const float* __restrict__ o_b2,
    const float* __restrict__ o_g2, const float* __restrict__ o_be2,
    const float* __restrict__ o_w3, const float* __restrict__ o_b3,
    float* __restrict__ out, float* __restrict__ sl1_part)
{
    __shared__ float tx[Mm], ty[Mm];
    int b = blockIdx.x, tid = threadIdx.x;
    const float* basev = baseo + b * Hh;

    int idx;
    if (tid < Mm)        idx = selidx_g[b * Mm + tid];
    else if (tid == Mm)  idx = gidx_g[b];
    else                 idx = 0;
    long row = (long)b * Nn + idx;

    float o0, o1;
    off_mlp_row(row, cand, basev, o_w1, o_g1, o_be1, o_w2, o_b2, o_g2, o_be2, o_w3, o_b3, o0, o1);

    if (tid < Mm) {
        tx[tid] = cand[row * 2 + 0] + o0;
        ty[tid] = cand[row * 2 + 1] + o1;
    } else if (tid == Mm) {
        float s1 = 0.f;
        float d0 = o0 - off_gt[b * 2 + 0];
        float ad0 = fabsf(d0);
        s1 += (ad0 < 1.f) ? 0.5f * d0 * d0 : ad0 - 0.5f;
        float d1 = o1 - off_gt[b * 2 + 1];
        float ad1 = fabsf(d1);
        s1 += (ad1 < 1.f) ? 0.5f * d1 * d1 : ad1 - 0.5f;
        sl1_part[b] = s1;
    }
    __syncthreads();
    if (tid == 0) {
        float sx[6], sy[6];
        #pragma unroll
        for (int k = 0; k < 6; ++k) { sx[k] = tx[k]; sy[k] = ty[k]; }
        int cnt = 1;
        for (int i = 1; i < Mm; ++i) {
            bool close = false;
            #pragma unroll
            for (int k = 0; k < 6; ++k) {
                float dx = sx[k] - tx[i], dy = sy[k] - ty[i];
                close = close || ((k < cnt) && (dx * dx + dy * dy < 2.0f));
            }
            if (!close && cnt < 6) { sx[cnt] = tx[i]; sy[cnt] = ty[i]; cnt++; }
        }
        #pragma unroll
        for (int k = 0; k < 6; ++k) {
            out[(b * 6 + k) * 2 + 0] = sx[k];
            out[(b * 6 + k) * 2 + 1] = sy[k];
        }
    }
}

// ---------------- K5: final loss (parallel) ----------------
__global__ __launch_bounds__(256) void k_loss(const float* __restrict__ bce_part,
                                              const float* __restrict__ sl1_part,
                                              float* __restrict__ out) {
    __shared__ float redb[4], reds[4];
    int tid = threadIdx.x, wave = tid >> 6, lane = tid & 63;
    float sb = bce_part[tid];
    float ss = sl1_part[tid];
    #pragma unroll
    for (int mm = 1; mm < 64; mm <<= 1) { sb += __shfl_xor(sb, mm); ss += __shfl_xor(ss, mm); }
    if (lane == 0) { redb[wave] = sb; reds[wave] = ss; }
    __syncthreads();
    if (tid == 0) {
        float tb = ((redb[0] + redb[1]) + redb[2]) + redb[3];
        float ts = ((reds[0] + reds[1]) + reds[2]) + reds[3];
        out[0] = -tb / (float)(Bb * Nn) + ts / (float)(Bb * 2);
    }
}

extern "C" void kernel_launch(void* const* d_in, const int* in_sizes, int n_in,
                              void* d_out, int out_size, void* d_ws, size_t ws_size,
                              hipStream_t stream) {
    const float* feat  = (const float*)d_in[0];
    const float* cand  = (const float*)d_in[1];
    const float* mask  = (const float*)d_in[2];
    const float* gt    = (const float*)d_in[3];
    const float* ogt   = (const float*)d_in[4];
    const float* p_w1  = (const float*)d_in[5];
    const float* p_b1  = (const float*)d_in[6];
    const float* p_g1  = (const float*)d_in[7];
    const float* p_be1 = (const float*)d_in[8];
    const float* p_w2  = (const float*)d_in[9];
    const float* p_b2  = (const float*)d_in[10];
    const float* p_g2  = (const float*)d_in[11];
    const float* p_be2 = (const float*)d_in[12];
    const float* p_w3  = (const float*)d_in[13];
    const float* p_b3  = (const float*)d_in[14];
    const float* o_w1  = (const float*)d_in[15];
    const float* o_b1  = (const float*)d_in[16];
    const float* o_g1  = (const float*)d_in[17];
    const float* o_be1 = (const float*)d_in[18];
    const float* o_w2  = (const float*)d_in[19];
    const float* o_g2  = (const float*)d_in[20];   // NOTE: dict order puts o_g2 before o_b2
    const float* o_b2  = (const float*)d_in[21];
    const float* o_be2 = (const float*)d_in[22];
    const float* o_w3  = (const float*)d_in[23];
    const float* o_b3  = (const float*)d_in[24];

    float* ws       = (float*)d_ws;
    float* basep    = ws;                        // B*H
    float* baseo    = basep + Bb * Hh;           // B*H
    float* logits   = baseo + Bb * Hh;           // B*N
    float* bce_part = logits + (long)Bb * Nn;    // B
    float* sl1_part = bce_part + Bb;             // B
    int*   selidx_g = (int*)(sl1_part + Bb);     // B*M ints
    int*   gidx_g   = selidx_g + Bb * Mm;        // B ints

    float* out = (float*)d_out;                  // (B,6,2) floats then loss scalar

    k_base<<<Bb, 128, 0, stream>>>(feat, p_w1, p_b1, o_w1, o_b1, basep, baseo);
    k_mlp_p<<<Bb * 8, 256, 0, stream>>>(cand, basep,
        p_w1, p_g1, p_be1, p_w2, p_b2, p_g2, p_be2, p_w3, p_b3, logits);
    k_post<<<Bb / 4, 256, 0, stream>>>(logits, mask, gt, bce_part, selidx_g, gidx_g);
    k_off<<<Bb, 64, 0, stream>>>(cand, baseo, selidx_g, gidx_g, ogt,
        o_w1, o_g1, o_be1, o_w2, o_b2, o_g2, o_be2, o_w3, o_b3, out, sl1_part);
    k_loss<<<1, 256, 0, stream>>>(bce_part, sl1_part, out + Bb * 6 * 2);
}

// Round 12
// 162.744 us; speedup vs baseline: 2.1036x; 1.0529x over previous
//
#include <hip/hip_runtime.h>
#include <hip/hip_bf16.h>
#include <math.h>

#define Bb 256
#define Nn 2048
#define Cc 128
#define Hh 64
#define Mm 50

// ---------------- K1: per-batch feat @ W1[:128] + b1 for BOTH MLPs ----------------
__global__ __launch_bounds__(128) void k_base(const float* __restrict__ feat,
                                              const float* __restrict__ p_w1,
                                              const float* __restrict__ p_b1,
                                              const float* __restrict__ o_w1,
                                              const float* __restrict__ o_b1,
                                              float* __restrict__ basep,
                                              float* __restrict__ baseo) {
    int b = blockIdx.x, tid = threadIdx.x;
    int k = tid & 63;
    bool lo = tid < 64;                     // wave-uniform select
    const float* w1 = lo ? p_w1 : o_w1;
    const float* b1 = lo ? p_b1 : o_b1;
    float* dst = lo ? basep : baseo;
    const float* f = feat + b * Cc;
    float s = b1[k];
    #pragma unroll 8
    for (int c = 0; c < Cc; ++c) s = fmaf(f[c], w1[c * Hh + k], s);
    dst[b * Hh + k] = s;
}

// ---------------- K2: prob MLP, thread-per-row, ROLLED j-loops (R11-proven) ----------------
__global__ __launch_bounds__(256, 1) void k_mlp_p(
    const float* __restrict__ cand, const float* __restrict__ basep,
    const float* __restrict__ p_w1, const float* __restrict__ p_g1, const float* __restrict__ p_be1,
    const float* __restrict__ p_w2, const float* __restrict__ p_b2,
    const float* __restrict__ p_g2, const float* __restrict__ p_be2,
    const float* __restrict__ p_w3, const float* __restrict__ p_b3,
    float* __restrict__ logits)
{
    int tid = threadIdx.x;
    int b = blockIdx.x >> 3;                 // 8 blocks x 256 threads = 2048 rows/batch
    int n = ((blockIdx.x & 7) << 8) + tid;
    long row = (long)b * Nn + n;
    float2 c2 = ((const float2*)cand)[row];
    float cx = c2.x, cy = c2.y;
    const float* basev = basep + b * Hh;
    const float* u = p_w1 + 128 * Hh;
    const float* v = p_w1 + 129 * Hh;

    // ---- LN1 stats: rolled, exact sequential j order ----
    float sum = 0.f, sq = 0.f;
    #pragma unroll 1
    for (int j = 0; j < Hh; ++j) {
        float t = fmaf(cy, v[j], fmaf(cx, u[j], basev[j]));
        sum += t;
        sq = fmaf(t, t, sq);
    }
    float mu = sum * (1.f / Hh);
    float rstd = rsqrtf(sq * (1.f / Hh) - mu * mu + 1e-5f);

    // ---- layer 2: rolled j, a_j rematerialized, 64 literal-index FMAs ----
    float h[Hh];
    #pragma unroll
    for (int i = 0; i < Hh; ++i) h[i] = 0.f;
    #pragma unroll 1
    for (int j = 0; j < Hh; ++j) {
        float t = fmaf(cy, v[j], fmaf(cx, u[j], basev[j]));
        float a = fmaxf(fmaf((t - mu) * rstd, p_g1[j], p_be1[j]), 0.f);
        const float* w2r = p_w2 + j * Hh;
        #pragma unroll
        for (int i = 0; i < Hh; ++i) h[i] = fmaf(a, w2r[i], h[i]);
    }

    // ---- bias + LN2 stats (reference order) ----
    float sum2 = 0.f, sq2 = 0.f;
    #pragma unroll
    for (int i = 0; i < Hh; ++i) {
        float hv = h[i] + p_b2[i];
        h[i] = hv;
        sum2 += hv;
        sq2 = fmaf(hv, hv, sq2);
    }
    float mu2 = sum2 * (1.f / Hh);
    float rstd2 = rsqrtf(sq2 * (1.f / Hh) - mu2 * mu2 + 1e-5f);

    // ---- head ----
    float lg = p_b3[0];
    #pragma unroll
    for (int i = 0; i < Hh; ++i) {
        float aa = fmaxf(fmaf((h[i] - mu2) * rstd2, p_g2[i], p_be2[i]), 0.f);
        lg = fmaf(aa, p_w3[i], lg);
    }
    logits[row] = lg;
}

// ---------------- K3: block-per-batch softmax + BCE partial + top-50 (R5-proven) ----------------
__global__ __launch_bounds__(256) void k_post(
    const float* __restrict__ logits, const float* __restrict__ mask,
    const float* __restrict__ gt,
    float* __restrict__ bce_part, int* __restrict__ selidx_g, int* __restrict__ gidx_g)
{
    __shared__ float vals[Nn];          // p per candidate
    __shared__ float redf[4];
    __shared__ float wvv[4]; __shared__ int wvi[4];
    __shared__ int   gidx_sh;
    __shared__ int   wini_sh;
    __shared__ int   selidx[Mm];

    int b = blockIdx.x, tid = threadIdx.x;
    int wave = tid >> 6, lane = tid & 63;
    const float* lg = logits + (long)b * Nn;
    const float* mk = mask + (long)b * Nn;

    // ---- max ----
    float xv[8];
    float mx = -1e30f;
    #pragma unroll
    for (int k = 0; k < 8; ++k) {
        int n = tid + k * 256;
        xv[k] = lg[n] + mk[n];
        mx = fmaxf(mx, xv[k]);
    }
    #pragma unroll
    for (int m = 1; m < 64; m <<= 1) mx = fmaxf(mx, __shfl_xor(mx, m));
    if (lane == 0) redf[wave] = mx;
    __syncthreads();
    float m = fmaxf(fmaxf(redf[0], redf[1]), fmaxf(redf[2], redf[3]));
    __syncthreads();

    // ---- exp + sum ----
    float ev[8]; float es = 0.f;
    #pragma unroll
    for (int k = 0; k < 8; ++k) { ev[k] = expf(xv[k] - m); es += ev[k]; }
    #pragma unroll
    for (int mm = 1; mm < 64; mm <<= 1) es += __shfl_xor(es, mm);
    if (lane == 0) redf[wave] = es;
    __syncthreads();
    float invZ = 1.f / (((redf[0] + redf[1]) + redf[2]) + redf[3]);

    // ---- p, BCE partial, gt index ----
    const float* g = gt + (long)b * Nn;
    float bs = 0.f;
    #pragma unroll
    for (int k = 0; k < 8; ++k) {
        int n = tid + k * 256;
        float pv = ev[k] * invZ;
        vals[n] = pv;
        float gv = g[n];
        float lp = fmaxf(logf(pv), -100.f);
        float l1p = fmaxf(log1pf(-pv), -100.f);
        bs += gv * lp + (1.f - gv) * l1p;
        if (gv > 0.5f) gidx_sh = n;     // one-hot: exactly one writer
    }
    #pragma unroll
    for (int mm = 1; mm < 64; mm <<= 1) bs += __shfl_xor(bs, mm);
    if (lane == 0) redf[wave] = bs;
    __syncthreads();
    if (tid == 0) {
        bce_part[b] = ((redf[0] + redf[1]) + redf[2]) + redf[3];
        gidx_g[b] = gidx_sh;
    }

    // ---- top-50 (exact lax.top_k order: desc value, asc index on ties) ----
    float bv = -1.f; int bi = 0x7fffffff;
    #pragma unroll
    for (int k = 0; k < 8; ++k) {
        int n = tid + k * 256;          // ascending n per thread -> min idx kept on ties
        float v = vals[n];
        if (v > bv) { bv = v; bi = n; }
    }
    for (int it = 0; it < Mm; ++it) {
        float rv = bv; int ri = bi;
        #pragma unroll
        for (int mm = 1; mm < 64; mm <<= 1) {
            float v2 = __shfl_xor(rv, mm); int i2 = __shfl_xor(ri, mm);
            if (v2 > rv || (v2 == rv && i2 < ri)) { rv = v2; ri = i2; }
        }
        if (lane == 0) { wvv[wave] = rv; wvi[wave] = ri; }
        __syncthreads();                 // A: wvv/wvi visible to tid0
        if (tid == 0) {
            float wv = wvv[0]; int wi = wvi[0];
            #pragma unroll
            for (int k = 1; k < 4; ++k) {
                if (wvv[k] > wv || (wvv[k] == wv && wvi[k] < wi)) { wv = wvv[k]; wi = wvi[k]; }
            }
            wini_sh = wi;
            selidx[it] = wi;
        }
        __syncthreads();                 // B: wini_sh visible to all
        int wi = wini_sh;
        if ((wi & 255) == tid) {         // owner: remove + rescan local 8
            vals[wi] = -1.f;
            bv = -1.f; bi = 0x7fffffff;
            #pragma unroll
            for (int k = 0; k < 8; ++k) {
                int n = tid + k * 256;
                float v = vals[n];
                if (v > bv) { bv = v; bi = n; }
            }
        }
    }
    if (tid < Mm) selidx_g[b * Mm + tid] = selidx[tid];
}

// ---------------- offset MLP for one row (full unroll, bit-identical math) ----------------
__device__ __forceinline__ void off_mlp_row(
    long row, const float* __restrict__ cand, const float* basev,
    const float* __restrict__ o_w1, const float* __restrict__ o_g1, const float* __restrict__ o_be1,
    const float* __restrict__ o_w2, const float* __restrict__ o_b2,
    const float* __restrict__ o_g2, const float* __restrict__ o_be2,
    const float* __restrict__ o_w3, const float* __restrict__ o_b3,
    float& o0, float& o1)
{
    float cx = cand[row * 2 + 0];
    float cy = cand[row * 2 + 1];
    const float* u = o_w1 + 128 * Hh;
    const float* v = o_w1 + 129 * Hh;
    float a[Hh];
    float sum = 0.f, sq = 0.f;
    #pragma unroll
    for (int j = 0; j < Hh; ++j) {
        float t = fmaf(cy, v[j], fmaf(cx, u[j], basev[j]));
        a[j] = t;
        sum += t;
        sq = fmaf(t, t, sq);
    }
    float mu = sum * (1.f / Hh);
    float rstd = rsqrtf(sq * (1.f / Hh) - mu * mu + 1e-5f);
    #pragma unroll
    for (int j = 0; j < Hh; ++j)
        a[j] = fmaxf(fmaf((a[j] - mu) * rstd, o_g1[j], o_be1[j]), 0.f);
    float h[Hh];
    #pragma unroll
    for (int i = 0; i < Hh; ++i) h[i] = 0.f;
    #pragma unroll
    for (int j = 0; j < Hh; ++j) {
        float av = a[j];
        const float* w2r = o_w2 + j * Hh;
        #pragma unroll
        for (int i = 0; i < Hh; ++i) h[i] = fmaf(av, w2r[i], h[i]);
    }
    float sum2 = 0.f, sq2 = 0.f;
    #pragma unroll
    for (int i = 0; i < Hh; ++i) {
        float hv = h[i] + o_b2[i];
        h[i] = hv;
        sum2 += hv;
        sq2 = fmaf(hv, hv, sq2);
    }
    float mu2 = sum2 * (1.f / Hh);
    float rstd2 = rsqrtf(sq2 * (1.f / Hh) - mu2 * mu2 + 1e-5f);
    o0 = o_b3[0]; o1 = o_b3[1];
    #pragma unroll
    for (int i = 0; i < Hh; ++i) {
        float aa = fmaxf(fmaf((h[i] - mu2) * rstd2, o_g2[i], o_be2[i]), 0.f);
        o0 = fmaf(aa, o_w3[i * 2 + 0], o0);
        o1 = fmaf(aa, o_w3[i * 2 + 1], o1);
    }
}

// ---------------- K4: offset MLP on 51 rows/batch + gather + NMS + SL1 ----------------
__global__ __launch_bounds__(64, 1) void k_off(
    const float* __restrict__ cand, const float* __restrict__ baseo,
    const int* __restrict__ selidx_g, const int* __restrict__ gidx_g,
    const float* __restrict__ off_gt,
    const float* __restrict__ o_w1, const float* __restrict__ o_g1, const float* __restrict__ o_be1,
    const float* __restrict__ o_w2, const float* __restrict__ o_b2,
    const float* __restrict__ o_g2, const float* __restrict__ o_be2,
    const float* __restrict__ o_w3, const float* __restrict__ o_b3,
    float* __restrict__ out, float* __restrict__ sl1_part)
{
    __shared__ float tx[Mm], ty[Mm];
    int b = blockIdx.x, tid = threadIdx.x;
    const float* basev = baseo + b * Hh;

    int idx;
    if (tid < Mm)        idx = selidx_g[b * Mm + tid];
    else if (tid == Mm)  idx = gidx_g[b];
    else                 idx = 0;
    long row = (long)b * Nn + idx;

    float o0, o1;
    off_mlp_row(row, cand, basev, o_w1, o_g1, o_be1, o_w2, o_b2, o_g2, o_be2, o_w3, o_b3, o0, o1);

    if (tid < Mm) {
        tx[tid] = cand[row * 2 + 0] + o0;
        ty[tid] = cand[row * 2 + 1] + o1;
    } else if (tid == Mm) {
        float s1 = 0.f;
        float d0 = o0 - off_gt[b * 2 + 0];
        float ad0 = fabsf(d0);
        s1 += (ad0 < 1.f) ? 0.5f * d0 * d0 : ad0 - 0.5f;
        float d1 = o1 - off_gt[b * 2 + 1];
        float ad1 = fabsf(d1);
        s1 += (ad1 < 1.f) ? 0.5f * d1 * d1 : ad1 - 0.5f;
        sl1_part[b] = s1;
    }
    __syncthreads();
    if (tid == 0) {
        float sx[6], sy[6];
        #pragma unroll
        for (int k = 0; k < 6; ++k) { sx[k] = tx[k]; sy[k] = ty[k]; }
        int cnt = 1;
        for (int i = 1; i < Mm; ++i) {
            bool close = false;
            #pragma unroll
            for (int k = 0; k < 6; ++k) {
                float dx = sx[k] - tx[i], dy = sy[k] - ty[i];
                close = close || ((k < cnt) && (dx * dx + dy * dy < 2.0f));
            }
            if (!close && cnt < 6) { sx[cnt] = tx[i]; sy[cnt] = ty[i]; cnt++; }
        }
        #pragma unroll
        for (int k = 0; k < 6; ++k) {
            out[(b * 6 + k) * 2 + 0] = sx[k];
            out[(b * 6 + k) * 2 + 1] = sy[k];
        }
    }
}

// ---------------- K5: final loss (parallel) ----------------
__global__ __launch_bounds__(256) void k_loss(const float* __restrict__ bce_part,
                                              const float* __restrict__ sl1_part,
                                              float* __restrict__ out) {
    __shared__ float redb[4], reds[4];
    int tid = threadIdx.x, wave = tid >> 6, lane = tid & 63;
    float sb = bce_part[tid];
    float ss = sl1_part[tid];
    #pragma unroll
    for (int mm = 1; mm < 64; mm <<= 1) { sb += __shfl_xor(sb, mm); ss += __shfl_xor(ss, mm); }
    if (lane == 0) { redb[wave] = sb; reds[wave] = ss; }
    __syncthreads();
    if (tid == 0) {
        float tb = ((redb[0] + redb[1]) + redb[2]) + redb[3];
        float ts = ((reds[0] + reds[1]) + reds[2]) + reds[3];
        out[0] = -tb / (float)(Bb * Nn) + ts / (float)(Bb * 2);
    }
}

extern "C" void kernel_launch(void* const* d_in, const int* in_sizes, int n_in,
                              void* d_out, int out_size, void* d_ws, size_t ws_size,
                              hipStream_t stream) {
    const float* feat  = (const float*)d_in[0];
    const float* cand  = (const float*)d_in[1];
    const float* mask  = (const float*)d_in[2];
    const float* gt    = (const float*)d_in[3];
    const float* ogt   = (const float*)d_in[4];
    const float* p_w1  = (const float*)d_in[5];
    const float* p_b1  = (const float*)d_in[6];
    const float* p_g1  = (const float*)d_in[7];
    const float* p_be1 = (const float*)d_in[8];
    const float* p_w2  = (const float*)d_in[9];
    const float* p_b2  = (const float*)d_in[10];
    const float* p_g2  = (const float*)d_in[11];
    const float* p_be2 = (const float*)d_in[12];
    const float* p_w3  = (const float*)d_in[13];
    const float* p_b3  = (const float*)d_in[14];
    const float* o_w1  = (const float*)d_in[15];
    const float* o_b1  = (const float*)d_in[16];
    const float* o_g1  = (const float*)d_in[17];
    const float* o_be1 = (const float*)d_in[18];
    const float* o_w2  = (const float*)d_in[19];
    const float* o_g2  = (const float*)d_in[20];   // NOTE: dict order puts o_g2 before o_b2
    const float* o_b2  = (const float*)d_in[21];
    const float* o_be2 = (const float*)d_in[22];
    const float* o_w3  = (const float*)d_in[23];
    const float* o_b3  = (const float*)d_in[24];

    float* ws       = (float*)d_ws;
    float* basep    = ws;                        // B*H
    float* baseo    = basep + Bb * Hh;           // B*H
    float* logits   = baseo + Bb * Hh;           // B*N
    float* bce_part = logits + (long)Bb * Nn;    // B
    float* sl1_part = bce_part + Bb;             // B
    int*   selidx_g = (int*)(sl1_part + Bb);     // B*M ints
    int*   gidx_g   = selidx_g + Bb * Mm;        // B ints

    float* out = (float*)d_out;                  // (B,6,2) floats then loss scalar

    k_base<<<Bb, 128, 0, stream>>>(feat, p_w1, p_b1, o_w1, o_b1, basep, baseo);
    k_mlp_p<<<Bb * 8, 256, 0, stream>>>(cand, basep,
        p_w1, p_g1, p_be1, p_w2, p_b2, p_g2, p_be2, p_w3, p_b3, logits);
    k_post<<<Bb, 256, 0, stream>>>(logits, mask, gt, bce_part, selidx_g, gidx_g);
    k_off<<<Bb, 64, 0, stream>>>(cand, baseo, selidx_g, gidx_g, ogt,
        o_w1, o_g1, o_be1, o_w2, o_b2, o_g2, o_be2, o_w3, o_b3, out, sl1_part);
    k_loss<<<1, 256, 0, stream>>>(bce_part, sl1_part, out + Bb * 6 * 2);
}